// Round 10
// baseline (3608.577 us; speedup 1.0000x reference)
//
#include <hip/hip_runtime.h>
#include <hip/hip_fp16.h>

#define HID 64
#define BIN_SHIFT 7
#define BIN_SIZE  128          // 1 << BIN_SHIFT (dst nodes per bin)
#define ASTRIDE   66           // acc row stride in f32 words (pad: 2-way max)
#define SC_TILE   8192         // edges per workgroup in bin_scatter

// R21: R20 REGRESSED (4-slot clamp/mask VALU cost > MLP gain); per-dst-wave
// agg has a structural ceiling (serial rp->esrc->shfl->gather + 24-inst fold
// per node; 3 attempts stuck 45-49us vs 16us HBM floor). Redesign:
// bin-local LDS-atomic aggregation, one 512-thr WG per 128-node bin:
//  - edge phase: 8-lane groups stream packed[] COALESCED (no rp/esrc/shfl;
//    src|dstlow in one word), gather 128B tmp row, ds_add_f32 into 33.8KB
//    LDS acc (WG-private, <=2-way bank conflict via 66-word stride).
//    4-deep unroll -> 4KB/wave in flight, ~24 waves/CU (4 WGs/CU LDS cap).
//  - flush: coalesced self-row + dinv/bias/relu + coalesced store.
// CSR build loses rp/scans/csr_scatter/esrc (dinv needs only deg); packed
// gets its own slot (tmp alias footgun gone). gemm_mfma (R17) unchanged.

typedef _Float16 f16x8 __attribute__((ext_vector_type(8)));
typedef float    f32x4 __attribute__((ext_vector_type(4)));

__global__ void zero_i(int* __restrict__ p, int n) {
    int i = blockIdx.x * 256 + threadIdx.x, st = gridDim.x * 256;
    for (; i < n; i += st) p[i] = 0;
}

__global__ void dinv_k(const int* __restrict__ deg, float* __restrict__ dinv, int N) {
    int i = blockIdx.x * 256 + threadIdx.x;
    if (i < N) dinv[i] = rsqrtf((float)deg[i] + 1.0f);
}

// ---- W fragment prep: wfrag[layer][ks][ct][lane][8] fp16 ----
__global__ void wfrag_prep(const float* __restrict__ W_in, const float* __restrict__ W_h,
                           const float* __restrict__ W_out, __half* __restrict__ wfrag) {
    int s = blockIdx.x, l = threadIdx.x;
    const float* W; int base, ls;
    if (s < 16)      { W = W_in;                      base = 0;                ls = s; }
    else if (s < 40) { int t = s - 16; int L = t >> 3;
                       W = W_h + (size_t)L * 64 * 64; base = 1024 + L * 512;   ls = t & 7; }
    else             { W = W_out;                     base = 2560;             ls = s - 40; }
    int ks = ls >> 2, ct = ls & 3;
    int col = ct * 16 + (l & 15);
    int k0  = ks * 32 + (l >> 4) * 8;
    __half v[8];
    #pragma unroll
    for (int j = 0; j < 8; ++j) v[j] = __float2half_rn(W[(size_t)(k0 + j) * HID + col]);
    *(uint4*)&wfrag[(size_t)(base + ls * 64 + l) * 8] = *(uint4*)v;
}

// ---- MFMA GEMM: out[N,64](fp16) = (H[N,K] @ W[K,64]) * dinv[row] ----
template<bool IN32, int NKS>
__global__ __launch_bounds__(256)
void gemm_mfma(const void* __restrict__ Hin, const __half* __restrict__ wfl,
               const float* __restrict__ dinv, __half* __restrict__ out, int N) {
    const int l  = threadIdx.x & 63;
    const int wv = threadIdx.x >> 6;
    const int rA = l & 15;        // A row within frag / C col
    const int gK = l >> 4;        // k-group / C row-group
    const int rb = blockIdx.x * 128 + wv * 32;

    f16x8 bf[NKS][4];
    #pragma unroll
    for (int ks = 0; ks < NKS; ++ks)
        #pragma unroll
        for (int ct = 0; ct < 4; ++ct)
            bf[ks][ct] = *(const f16x8*)(wfl + (size_t)((ks * 4 + ct) * 64 + l) * 8);

    f16x8 af[NKS][2];
    #pragma unroll
    for (int rt = 0; rt < 2; ++rt) {
        int r = rb + rt * 16 + rA; if (r > N - 1) r = N - 1;
        if (IN32) {
            const float* H = (const float*)Hin;
            const float* p = H + (size_t)r * (NKS * 32) + gK * 8;
            #pragma unroll
            for (int ks = 0; ks < NKS; ++ks) {
                f32x4 a = *(const f32x4*)(p + ks * 32);
                f32x4 b = *(const f32x4*)(p + ks * 32 + 4);
                f16x8 t;
                t[0] = (_Float16)a[0]; t[1] = (_Float16)a[1];
                t[2] = (_Float16)a[2]; t[3] = (_Float16)a[3];
                t[4] = (_Float16)b[0]; t[5] = (_Float16)b[1];
                t[6] = (_Float16)b[2]; t[7] = (_Float16)b[3];
                af[ks][rt] = t;
            }
        } else {
            const __half* H = (const __half*)Hin;
            #pragma unroll
            for (int ks = 0; ks < NKS; ++ks)
                af[ks][rt] = *(const f16x8*)(H + (size_t)r * HID + ks * 32 + gK * 8);
        }
    }

    f32x4 acc[2][4];
    #pragma unroll
    for (int rt = 0; rt < 2; ++rt)
        #pragma unroll
        for (int ct = 0; ct < 4; ++ct)
            acc[rt][ct] = (f32x4){0.f, 0.f, 0.f, 0.f};

    #pragma unroll
    for (int ks = 0; ks < NKS; ++ks)
        #pragma unroll
        for (int rt = 0; rt < 2; ++rt)
            #pragma unroll
            for (int ct = 0; ct < 4; ++ct)
                acc[rt][ct] = __builtin_amdgcn_mfma_f32_16x16x32_f16(
                    af[ks][rt], bf[ks][ct], acc[rt][ct], 0, 0, 0);

    #pragma unroll
    for (int rt = 0; rt < 2; ++rt) {
        int r0 = rb + rt * 16 + gK * 4;
        float dv[4];
        #pragma unroll
        for (int j = 0; j < 4; ++j) dv[j] = dinv[min(r0 + j, N - 1)];
        #pragma unroll
        for (int ct = 0; ct < 4; ++ct)
            #pragma unroll
            for (int j = 0; j < 4; ++j) {
                int r = r0 + j;
                if (r < N)
                    out[(size_t)r * HID + ct * 16 + rA] =
                        __float2half_rn(acc[rt][ct][j] * dv[j]);
            }
    }
}

// ---- bin histogram: LDS hist per wg, one global atomic per (wg,bin) ----
__global__ void bin_count(const int* __restrict__ dst, int* __restrict__ binCount,
                          int E, int nbins) {
    __shared__ int c[1024];
    for (int i = threadIdx.x; i < nbins; i += 256) c[i] = 0;
    __syncthreads();
    int chunk = (E + gridDim.x - 1) / gridDim.x;
    int s0 = blockIdx.x * chunk, s1 = min(E, s0 + chunk);
    for (int e = s0 + threadIdx.x; e < s1; e += 256)
        atomicAdd(&c[dst[e] >> BIN_SHIFT], 1);
    __syncthreads();
    for (int i = threadIdx.x; i < nbins; i += 256)
        if (c[i]) atomicAdd(&binCount[i], c[i]);
}

// ---- exclusive scan over bins (<=1024), init binCursor = binOff ----
__global__ void bin_scan(const int* __restrict__ binCount, int* __restrict__ binOff,
                         int* __restrict__ binCursor, int nb, int E) {
    __shared__ int s[256];
    int t = threadIdx.x, base = t * 4;
    int v0 = 0, v1 = 0, v2 = 0, v3 = 0;
    if (base + 0 < nb) v0 = binCount[base + 0];
    if (base + 1 < nb) v1 = binCount[base + 1];
    if (base + 2 < nb) v2 = binCount[base + 2];
    if (base + 3 < nb) v3 = binCount[base + 3];
    int sum = v0 + v1 + v2 + v3;
    s[t] = sum; __syncthreads();
    for (int off = 1; off < 256; off <<= 1) {
        int x = (t >= off) ? s[t - off] : 0;
        __syncthreads(); s[t] += x; __syncthreads();
    }
    int run = s[t] - sum;
    if (base + 0 < nb) { binOff[base + 0] = run; binCursor[base + 0] = run; } run += v0;
    if (base + 1 < nb) { binOff[base + 1] = run; binCursor[base + 1] = run; } run += v1;
    if (base + 2 < nb) { binOff[base + 2] = run; binCursor[base + 2] = run; } run += v2;
    if (base + 3 < nb) { binOff[base + 3] = run; binCursor[base + 3] = run; } run += v3;
    if (t == 0) binOff[nb] = E;
}

// ---- bin scatter: per-tile LDS count -> segment reservation -> append ----
__global__ void bin_scatter(const int* __restrict__ src, const int* __restrict__ dst,
                            int* __restrict__ binCursor, unsigned* __restrict__ packed,
                            int E, int nbins) {
    __shared__ int cnt[1024];
    __shared__ int cur[1024];
    int t = threadIdx.x;
    int s0 = blockIdx.x * SC_TILE, s1 = min(E, s0 + SC_TILE);
    for (int i = t; i < nbins; i += 256) cnt[i] = 0;
    __syncthreads();
    for (int e = s0 + t; e < s1; e += 256)
        atomicAdd(&cnt[dst[e] >> BIN_SHIFT], 1);
    __syncthreads();
    for (int b = t; b < nbins; b += 256)
        cur[b] = cnt[b] ? atomicAdd(&binCursor[b], cnt[b]) : 0;
    __syncthreads();
    for (int e = s0 + t; e < s1; e += 256) {       // tile re-read is L2-hot
        int d = dst[e];
        int b = d >> BIN_SHIFT;
        int pos = atomicAdd(&cur[b], 1);
        packed[pos] = ((unsigned)src[e] << BIN_SHIFT) | (unsigned)(d & (BIN_SIZE - 1));
    }
}

// ---- per-bin degree count (dinv input): coalesced deg writes ----
__global__ void deg_bin(const unsigned* __restrict__ packed, const int* __restrict__ binOff,
                        int* __restrict__ deg, int N) {
    __shared__ int c[BIN_SIZE];
    int t = threadIdx.x, b = blockIdx.x;
    for (int i = t; i < BIN_SIZE; i += 256) c[i] = 0;
    int j0 = binOff[b], j1 = binOff[b + 1];
    __syncthreads();
    for (int j = j0 + t; j < j1; j += 256)
        atomicAdd(&c[packed[j] & (BIN_SIZE - 1)], 1);
    __syncthreads();
    int base = b << BIN_SHIFT;
    for (int i = t; i < BIN_SIZE; i += 256) {
        int nd = base + i;
        if (nd < N) deg[nd] = c[i];
    }
}

// ---- bin-local LDS-atomic aggregation: one WG per 128-node bin ----
// 8-lane group per edge: g=tid&7 owns cols 8g..8g+7. packed[] streamed
// coalesced; gathers 16B/lane; ds_add_f32 into WG-private acc. No shuffles.
// out = relu?( dinv[d] * (sum_j tmp[src_j] + tmp[d]) + bias )
__global__ __launch_bounds__(512)
void agg_bin(const __half* __restrict__ tmp, const unsigned* __restrict__ packed,
             const int* __restrict__ binOff, const float* __restrict__ dinv,
             const float* __restrict__ bias, float* __restrict__ outf,
             __half* __restrict__ houtp, int N, int do_relu) {
    __shared__ float acc[BIN_SIZE * ASTRIDE];     // 33792 B
    const int tid = threadIdx.x, b = blockIdx.x;
    const int g   = tid & 7;        // col group
    const int grp = tid >> 3;       // edge group 0..63

    for (int i = tid; i < BIN_SIZE * ASTRIDE; i += 512) acc[i] = 0.0f;
    __syncthreads();

    const int j0 = binOff[b], j1 = binOff[b + 1];
    // 4-deep unrolled edge loop: 4 (packed,gather) pairs in flight per group
    for (int j = j0 + grp; j < j1; j += 256) {
        int jB = j + 64, jC = j + 128, jD = j + 192;
        bool hB = jB < j1, hC = jC < j1, hD = jD < j1;
        unsigned pA = packed[j];
        unsigned pB = hB ? packed[jB] : 0;
        unsigned pC = hC ? packed[jC] : 0;
        unsigned pD = hD ? packed[jD] : 0;
        uint4 vA = ((const uint4*)(tmp + (size_t)(pA >> BIN_SHIFT) * HID))[g];
        uint4 vB = make_uint4(0,0,0,0), vC = make_uint4(0,0,0,0), vD = make_uint4(0,0,0,0);
        if (hB) vB = ((const uint4*)(tmp + (size_t)(pB >> BIN_SHIFT) * HID))[g];
        if (hC) vC = ((const uint4*)(tmp + (size_t)(pC >> BIN_SHIFT) * HID))[g];
        if (hD) vD = ((const uint4*)(tmp + (size_t)(pD >> BIN_SHIFT) * HID))[g];
        {
            int ab = (int)(pA & (BIN_SIZE - 1)) * ASTRIDE + g * 8;
            const __half2* h2 = (const __half2*)&vA;
            #pragma unroll
            for (int k = 0; k < 4; ++k) {
                float2 f = __half22float2(h2[k]);
                atomicAdd(&acc[ab + 2 * k],     f.x);
                atomicAdd(&acc[ab + 2 * k + 1], f.y);
            }
        }
        if (hB) {
            int ab = (int)(pB & (BIN_SIZE - 1)) * ASTRIDE + g * 8;
            const __half2* h2 = (const __half2*)&vB;
            #pragma unroll
            for (int k = 0; k < 4; ++k) {
                float2 f = __half22float2(h2[k]);
                atomicAdd(&acc[ab + 2 * k],     f.x);
                atomicAdd(&acc[ab + 2 * k + 1], f.y);
            }
        }
        if (hC) {
            int ab = (int)(pC & (BIN_SIZE - 1)) * ASTRIDE + g * 8;
            const __half2* h2 = (const __half2*)&vC;
            #pragma unroll
            for (int k = 0; k < 4; ++k) {
                float2 f = __half22float2(h2[k]);
                atomicAdd(&acc[ab + 2 * k],     f.x);
                atomicAdd(&acc[ab + 2 * k + 1], f.y);
            }
        }
        if (hD) {
            int ab = (int)(pD & (BIN_SIZE - 1)) * ASTRIDE + g * 8;
            const __half2* h2 = (const __half2*)&vD;
            #pragma unroll
            for (int k = 0; k < 4; ++k) {
                float2 f = __half22float2(h2[k]);
                atomicAdd(&acc[ab + 2 * k],     f.x);
                atomicAdd(&acc[ab + 2 * k + 1], f.y);
            }
        }
    }
    __syncthreads();

    // flush: (node, col-group) pairs; fully coalesced self-row read + store
    for (int idx = tid; idx < BIN_SIZE * 8; idx += 512) {
        int dl = idx >> 3, gg = idx & 7;
        int nd = (b << BIN_SHIFT) + dl;
        if (nd >= N) continue;
        uint4 sv = ((const uint4*)(tmp + (size_t)nd * HID))[gg];
        const __half2* sh = (const __half2*)&sv;
        int ab = dl * ASTRIDE + gg * 8;
        float o[8];
        #pragma unroll
        for (int k = 0; k < 4; ++k) {
            float2 f = __half22float2(sh[k]);
            o[2 * k]     = acc[ab + 2 * k]     + f.x;
            o[2 * k + 1] = acc[ab + 2 * k + 1] + f.y;
        }
        float di = dinv[nd];
        #pragma unroll
        for (int i = 0; i < 8; ++i) o[i] *= di;
        if (bias != nullptr) {
            #pragma unroll
            for (int i = 0; i < 8; ++i) o[i] += bias[gg * 8 + i];
        }
        if (do_relu) {
            #pragma unroll
            for (int i = 0; i < 8; ++i) o[i] = fmaxf(o[i], 0.0f);
        }
        if (houtp != nullptr) {
            __half2 ph[4];
            #pragma unroll
            for (int i = 0; i < 4; ++i)
                ph[i] = __halves2half2(__float2half_rn(o[2 * i]),
                                       __float2half_rn(o[2 * i + 1]));
            *(uint4*)&houtp[(size_t)nd * HID + gg * 8] = *(uint4*)ph;
        } else {
            float* orow = &outf[(size_t)nd * HID + gg * 8];
            *(float4*)orow       = make_float4(o[0], o[1], o[2], o[3]);
            *(float4*)(orow + 4) = make_float4(o[4], o[5], o[6], o[7]);
        }
    }
}

extern "C" void kernel_launch(void* const* d_in, const int* in_sizes, int n_in,
                              void* d_out, int out_size, void* d_ws, size_t ws_size,
                              hipStream_t stream) {
    const float* x     = (const float*)d_in[0];   // f32 [N,128]
    const int*   ei    = (const int*)d_in[1];     // int32 [2,E]
    const float* W_in  = (const float*)d_in[2];   // f32 [128,64]
    const float* b_in  = (const float*)d_in[3];   // f32 [64]
    const float* W_h   = (const float*)d_in[4];   // f32 [3,64,64]
    const float* b_h   = (const float*)d_in[5];   // f32 [3,64]
    const float* W_out = (const float*)d_in[6];   // f32 [64,64]

    const int K0 = in_sizes[2] / HID;   // 128
    const int N  = in_sizes[0] / K0;    // 100000
    const int E  = in_sizes[1] / 2;     // 1600000
    const int* srcp = ei;
    const int* dstp = ei + E;

    const int NH = N * HID;
    const size_t Npad = ((size_t)N + 255) & ~(size_t)255;
    const int nbins = (N + BIN_SIZE - 1) >> BIN_SHIFT;   // 782

    float*  ACC = (float*)d_out;                  // final output f32 [N,64]
    __half* h16 = (__half*)d_out;                 // intermediate H fp16 (same storage)

    // ws layout (~20.5MB, inside the proven region). packed NO LONGER
    // aliases tmp (it must persist across all agg launches).
    float*    dinv   = (float*)d_ws;              // Npad f32          0.4 MB
    __half*   tmp    = (__half*)(dinv + Npad);    // NH half          12.8 MB
    int*      degi   = (int*)(tmp + NH);          // Npad              0.4 MB
    unsigned* packed = (unsigned*)(degi + Npad);  // E u32             6.4 MB
    int*      binCount  = (int*)(packed + E);     // 1024
    int*      binOff    = binCount + 1024;        // 1025
    int*      binCursor = binOff + 1026;          // 1024
    uintptr_t wf_addr = (uintptr_t)(binCursor + 1024);
    wf_addr = (wf_addr + 15) & ~(uintptr_t)15;
    __half*   wfrag  = (__half*)wf_addr;          // 3072 x 8 fp16    48 KB

    const int tgrid = (N + 127) / 128;
    const int sgrid = (E + SC_TILE - 1) / SC_TILE;

    // ---- W fragment prep + counting-sort bin build (no per-dst CSR) ----
    wfrag_prep<<<48, 64, 0, stream>>>(W_in, W_h, W_out, wfrag);
    zero_i<<<1, 256, 0, stream>>>(binCount, nbins);
    bin_count<<<nbins, 256, 0, stream>>>(dstp, binCount, E, nbins);
    bin_scan<<<1, 256, 0, stream>>>(binCount, binOff, binCursor, nbins, E);
    bin_scatter<<<sgrid, 256, 0, stream>>>(srcp, dstp, binCursor, packed, E, nbins);
    deg_bin<<<nbins, 256, 0, stream>>>(packed, binOff, degi, N);
    dinv_k<<<(N + 255) / 256, 256, 0, stream>>>(degi, dinv, N);

    // ---- 5 GCN convs (MFMA GEMMs; fp16 inter-layer H) ----
    gemm_mfma<true, 4><<<tgrid, 256, 0, stream>>>(x, wfrag, dinv, tmp, N);
    agg_bin<<<nbins, 512, 0, stream>>>(tmp, packed, binOff, dinv, b_in, nullptr, h16, N, 0);
    for (int l = 0; l < 3; ++l) {
        gemm_mfma<false, 2><<<tgrid, 256, 0, stream>>>(
            h16, wfrag + (size_t)(1024 + l * 512) * 8, dinv, tmp, N);
        agg_bin<<<nbins, 512, 0, stream>>>(tmp, packed, binOff, dinv,
                                           b_h + (size_t)l * HID, nullptr, h16, N, 1);
    }
    gemm_mfma<false, 2><<<tgrid, 256, 0, stream>>>(
        h16, wfrag + (size_t)2560 * 8, dinv, tmp, N);
    agg_bin<<<nbins, 512, 0, stream>>>(tmp, packed, binOff, dinv, nullptr, ACC, nullptr, N, 0);
}

// Round 11
// 440.690 us; speedup vs baseline: 8.1885x; 8.1885x over previous
//
#include <hip/hip_runtime.h>
#include <hip/hip_fp16.h>

#define HID 64
#define BIN_SHIFT 9
#define BIN_SIZE  512          // 1 << BIN_SHIFT (dst nodes per bin)
#define SC_TILE   8192         // edges per workgroup in bin_scatter

// R22: R21 REGRESSED 15x (64 LDS-atomic f32 adds per edge at >=4-way bank
// conflict saturated the DS pipe; VALUBusy 1.1%). Reverted agg to R19-exact
// (45.2us, best). Consolidation: agg plateaus at 2.1-2.25 TB/s / 86.4MB
// FETCH across 3 designs == per-XCD table-refetch model => near random-
// gather ceiling. This round fixes the one clearly-suboptimal piece:
//  - csr_build fuses csr_count+dinv+scan1/2/3+csr_scatter into ONE kernel
//    per bin (LDS count -> LDS scan -> rp+dinv write -> LDS-cursor scatter).
//  - bin_count grid 196 -> 784 (chip has 256 CUs).
// gemm_mfma (R17) and agg_csr (R19) byte-identical.

typedef _Float16 f16x8 __attribute__((ext_vector_type(8)));
typedef float    f32x4 __attribute__((ext_vector_type(4)));

__global__ void zero_i(int* __restrict__ p, int n) {
    int i = blockIdx.x * 256 + threadIdx.x, st = gridDim.x * 256;
    for (; i < n; i += st) p[i] = 0;
}

// ---- W fragment prep: wfrag[layer][ks][ct][lane][8] fp16 ----
__global__ void wfrag_prep(const float* __restrict__ W_in, const float* __restrict__ W_h,
                           const float* __restrict__ W_out, __half* __restrict__ wfrag) {
    int s = blockIdx.x, l = threadIdx.x;
    const float* W; int base, ls;
    if (s < 16)      { W = W_in;                      base = 0;                ls = s; }
    else if (s < 40) { int t = s - 16; int L = t >> 3;
                       W = W_h + (size_t)L * 64 * 64; base = 1024 + L * 512;   ls = t & 7; }
    else             { W = W_out;                     base = 2560;             ls = s - 40; }
    int ks = ls >> 2, ct = ls & 3;
    int col = ct * 16 + (l & 15);
    int k0  = ks * 32 + (l >> 4) * 8;
    __half v[8];
    #pragma unroll
    for (int j = 0; j < 8; ++j) v[j] = __float2half_rn(W[(size_t)(k0 + j) * HID + col]);
    *(uint4*)&wfrag[(size_t)(base + ls * 64 + l) * 8] = *(uint4*)v;
}

// ---- MFMA GEMM: out[N,64](fp16) = (H[N,K] @ W[K,64]) * dinv[row] ----
template<bool IN32, int NKS>
__global__ __launch_bounds__(256)
void gemm_mfma(const void* __restrict__ Hin, const __half* __restrict__ wfl,
               const float* __restrict__ dinv, __half* __restrict__ out, int N) {
    const int l  = threadIdx.x & 63;
    const int wv = threadIdx.x >> 6;
    const int rA = l & 15;        // A row within frag / C col
    const int gK = l >> 4;        // k-group / C row-group
    const int rb = blockIdx.x * 128 + wv * 32;

    f16x8 bf[NKS][4];
    #pragma unroll
    for (int ks = 0; ks < NKS; ++ks)
        #pragma unroll
        for (int ct = 0; ct < 4; ++ct)
            bf[ks][ct] = *(const f16x8*)(wfl + (size_t)((ks * 4 + ct) * 64 + l) * 8);

    f16x8 af[NKS][2];
    #pragma unroll
    for (int rt = 0; rt < 2; ++rt) {
        int r = rb + rt * 16 + rA; if (r > N - 1) r = N - 1;
        if (IN32) {
            const float* H = (const float*)Hin;
            const float* p = H + (size_t)r * (NKS * 32) + gK * 8;
            #pragma unroll
            for (int ks = 0; ks < NKS; ++ks) {
                f32x4 a = *(const f32x4*)(p + ks * 32);
                f32x4 b = *(const f32x4*)(p + ks * 32 + 4);
                f16x8 t;
                t[0] = (_Float16)a[0]; t[1] = (_Float16)a[1];
                t[2] = (_Float16)a[2]; t[3] = (_Float16)a[3];
                t[4] = (_Float16)b[0]; t[5] = (_Float16)b[1];
                t[6] = (_Float16)b[2]; t[7] = (_Float16)b[3];
                af[ks][rt] = t;
            }
        } else {
            const __half* H = (const __half*)Hin;
            #pragma unroll
            for (int ks = 0; ks < NKS; ++ks)
                af[ks][rt] = *(const f16x8*)(H + (size_t)r * HID + ks * 32 + gK * 8);
        }
    }

    f32x4 acc[2][4];
    #pragma unroll
    for (int rt = 0; rt < 2; ++rt)
        #pragma unroll
        for (int ct = 0; ct < 4; ++ct)
            acc[rt][ct] = (f32x4){0.f, 0.f, 0.f, 0.f};

    #pragma unroll
    for (int ks = 0; ks < NKS; ++ks)
        #pragma unroll
        for (int rt = 0; rt < 2; ++rt)
            #pragma unroll
            for (int ct = 0; ct < 4; ++ct)
                acc[rt][ct] = __builtin_amdgcn_mfma_f32_16x16x32_f16(
                    af[ks][rt], bf[ks][ct], acc[rt][ct], 0, 0, 0);

    #pragma unroll
    for (int rt = 0; rt < 2; ++rt) {
        int r0 = rb + rt * 16 + gK * 4;
        float dv[4];
        #pragma unroll
        for (int j = 0; j < 4; ++j) dv[j] = dinv[min(r0 + j, N - 1)];
        #pragma unroll
        for (int ct = 0; ct < 4; ++ct)
            #pragma unroll
            for (int j = 0; j < 4; ++j) {
                int r = r0 + j;
                if (r < N)
                    out[(size_t)r * HID + ct * 16 + rA] =
                        __float2half_rn(acc[rt][ct][j] * dv[j]);
            }
    }
}

// ---- bin histogram: LDS hist per wg, one global atomic per (wg,bin) ----
__global__ void bin_count(const int* __restrict__ dst, int* __restrict__ binCount,
                          int E, int nbins) {
    __shared__ int c[1024];
    for (int i = threadIdx.x; i < nbins; i += 256) c[i] = 0;
    __syncthreads();
    int chunk = (E + gridDim.x - 1) / gridDim.x;
    int s0 = blockIdx.x * chunk, s1 = min(E, s0 + chunk);
    for (int e = s0 + threadIdx.x; e < s1; e += 256)
        atomicAdd(&c[dst[e] >> BIN_SHIFT], 1);
    __syncthreads();
    for (int i = threadIdx.x; i < nbins; i += 256)
        if (c[i]) atomicAdd(&binCount[i], c[i]);
}

// ---- exclusive scan over bins (<=1024), init binCursor = binOff ----
__global__ void bin_scan(const int* __restrict__ binCount, int* __restrict__ binOff,
                         int* __restrict__ binCursor, int nb, int E) {
    __shared__ int s[256];
    int t = threadIdx.x, base = t * 4;
    int v0 = 0, v1 = 0, v2 = 0, v3 = 0;
    if (base + 0 < nb) v0 = binCount[base + 0];
    if (base + 1 < nb) v1 = binCount[base + 1];
    if (base + 2 < nb) v2 = binCount[base + 2];
    if (base + 3 < nb) v3 = binCount[base + 3];
    int sum = v0 + v1 + v2 + v3;
    s[t] = sum; __syncthreads();
    for (int off = 1; off < 256; off <<= 1) {
        int x = (t >= off) ? s[t - off] : 0;
        __syncthreads(); s[t] += x; __syncthreads();
    }
    int run = s[t] - sum;
    if (base + 0 < nb) { binOff[base + 0] = run; binCursor[base + 0] = run; } run += v0;
    if (base + 1 < nb) { binOff[base + 1] = run; binCursor[base + 1] = run; } run += v1;
    if (base + 2 < nb) { binOff[base + 2] = run; binCursor[base + 2] = run; } run += v2;
    if (base + 3 < nb) { binOff[base + 3] = run; binCursor[base + 3] = run; } run += v3;
    if (t == 0) binOff[nb] = E;
}

// ---- bin scatter: per-tile LDS count -> segment reservation -> append ----
__global__ void bin_scatter(const int* __restrict__ src, const int* __restrict__ dst,
                            int* __restrict__ binCursor, unsigned* __restrict__ packed,
                            int E, int nbins) {
    __shared__ int cnt[1024];
    __shared__ int cur[1024];
    int t = threadIdx.x;
    int s0 = blockIdx.x * SC_TILE, s1 = min(E, s0 + SC_TILE);
    for (int i = t; i < nbins; i += 256) cnt[i] = 0;
    __syncthreads();
    for (int e = s0 + t; e < s1; e += 256)
        atomicAdd(&cnt[dst[e] >> BIN_SHIFT], 1);
    __syncthreads();
    for (int b = t; b < nbins; b += 256)
        cur[b] = cnt[b] ? atomicAdd(&binCursor[b], cnt[b]) : 0;
    __syncthreads();
    for (int e = s0 + t; e < s1; e += 256) {       // tile re-read is L2-hot
        int d = dst[e];
        int b = d >> BIN_SHIFT;
        int pos = atomicAdd(&cur[b], 1);
        packed[pos] = ((unsigned)src[e] << BIN_SHIFT) | (unsigned)(d & (BIN_SIZE - 1));
    }
}

// ---- fused per-bin CSR build: count -> scan -> rp+dinv -> scatter ----
// replaces csr_count + dinv_k + scan1/2/3 + csr_scatter (6 kernels -> 1).
__global__ void csr_build(const unsigned* __restrict__ packed, const int* __restrict__ binOff,
                          int* __restrict__ rp, int* __restrict__ esrc,
                          float* __restrict__ dinv, int N, int E) {
    __shared__ int c[BIN_SIZE];     // counts, then cursors
    __shared__ int off[BIN_SIZE];   // inclusive scan
    int t = threadIdx.x, b = blockIdx.x;
    int i0 = t, i1 = t + 256;
    c[i0] = 0; c[i1] = 0;
    __syncthreads();
    int j0 = binOff[b], j1 = binOff[b + 1];
    for (int j = j0 + t; j < j1; j += 256)
        atomicAdd(&c[packed[j] & (BIN_SIZE - 1)], 1);
    __syncthreads();
    off[i0] = c[i0]; off[i1] = c[i1];
    __syncthreads();
    for (int o = 1; o < BIN_SIZE; o <<= 1) {      // Hillis-Steele, 2 elems/thr
        int v0 = (i0 >= o) ? off[i0 - o] : 0;
        int v1 = (i1 >= o) ? off[i1 - o] : 0;
        __syncthreads();
        off[i0] += v0; off[i1] += v1;
        __syncthreads();
    }
    int base = b << BIN_SHIFT;
    #pragma unroll
    for (int q = 0; q < 2; ++q) {
        int i  = t + q * 256;
        int nd = base + i;
        int excl = off[i] - c[i];
        if (nd < N) {
            rp[nd]   = j0 + excl;
            dinv[nd] = rsqrtf((float)c[i] + 1.0f);
        }
        c[i] = j0 + excl;                          // cursor
    }
    if (b == 0 && t == 0) rp[N] = E;
    __syncthreads();
    for (int j = j0 + t; j < j1; j += 256) {
        unsigned p = packed[j];
        int dl = p & (BIN_SIZE - 1);
        int pos = atomicAdd(&c[dl], 1);
        esrc[pos] = (int)(p >> BIN_SHIFT);
    }
}

// ---- CSR aggregation: software-pipelined over nodes (R19-exact) ----
// lane group g=lane&7 owns cols 8g..8g+7; sub=lane>>3 picks the edge.
// rp[dn] prefetched a full node ahead; next esrc chunk prefetched under
// fold/write. All shuffles at full exec (wave-uniform sections).
__global__ void agg_csr(const __half* __restrict__ tmp, const int* __restrict__ rp,
                        const int* __restrict__ esrc, const float* __restrict__ dinv,
                        const float* __restrict__ bias, float* __restrict__ outf,
                        __half* __restrict__ houtp, int N, int do_relu) {
    const int wave = threadIdx.x >> 6;
    const int lane = threadIdx.x & 63;
    const int g    = lane & 7;       // col group
    const int sub  = lane >> 3;      // edge slot 0..7
    const int stride = gridDim.x * 4;

    int d = blockIdx.x * 4 + wave;
    if (d >= N) return;
    int j0 = rp[d], j1 = rp[d + 1];
    int sp = (j0 + lane < j1) ? esrc[j0 + lane] : 0;   // first chunk prefetch

    while (d < N) {
        const int dn = d + stride;
        int nj0 = 0, nj1 = 0;
        if (dn < N) { nj0 = rp[dn]; nj1 = rp[dn + 1]; }   // in flight during gathers

        // self-loop term (branchless: lanes sub!=0 contribute 0)
        uint4 vself = make_uint4(0, 0, 0, 0);
        if (sub == 0) vself = ((const uint4*)(tmp + (size_t)d * HID))[g];
        float acc[8];
        {
            const __half2* h2 = (const __half2*)&vself;
            #pragma unroll
            for (int i = 0; i < 4; ++i) {
                float2 f = __half22float2(h2[i]);
                acc[2 * i]     = f.x;
                acc[2 * i + 1] = f.y;
            }
        }

        int cs = sp, base = j0;
        while (base < j1) {
            int cnt = min(64, j1 - base);
            int jj = 0;
            for (; jj + 16 <= cnt; jj += 16) {       // 2-deep, unguarded
                int s0 = __shfl(cs, jj + sub);
                int s1 = __shfl(cs, jj + 8 + sub);
                uint4 v0 = ((const uint4*)(tmp + (size_t)s0 * HID))[g];
                uint4 v1 = ((const uint4*)(tmp + (size_t)s1 * HID))[g];
                const __half2* h0 = (const __half2*)&v0;
                const __half2* h1 = (const __half2*)&v1;
                #pragma unroll
                for (int i = 0; i < 4; ++i) {
                    float2 f0 = __half22float2(h0[i]);
                    float2 f1 = __half22float2(h1[i]);
                    acc[2 * i]     += f0.x + f1.x;
                    acc[2 * i + 1] += f0.y + f1.y;
                }
            }
            if (jj + 8 <= cnt) {                     // 1-deep, unguarded
                int s0 = __shfl(cs, jj + sub);
                uint4 v0 = ((const uint4*)(tmp + (size_t)s0 * HID))[g];
                const __half2* h0 = (const __half2*)&v0;
                #pragma unroll
                for (int i = 0; i < 4; ++i) {
                    float2 f = __half22float2(h0[i]);
                    acc[2 * i] += f.x; acc[2 * i + 1] += f.y;
                }
                jj += 8;
            }
            if (jj < cnt) {                          // clamped tail
                int e = jj + sub;
                int s0 = __shfl(cs, min(e, cnt - 1));   // full exec
                if (e < cnt) {
                    uint4 v = ((const uint4*)(tmp + (size_t)s0 * HID))[g];
                    const __half2* h2 = (const __half2*)&v;
                    #pragma unroll
                    for (int i = 0; i < 4; ++i) {
                        float2 f = __half22float2(h2[i]);
                        acc[2 * i] += f.x; acc[2 * i + 1] += f.y;
                    }
                }
            }
            base += 64;
            if (base < j1) {
                int rem = j1 - base;
                cs = (lane < rem) ? esrc[base + lane] : 0;
            }
        }

        // prefetch next node's first esrc chunk (nj0 arrived by now)
        int nsp = 0;
        if (dn < N) nsp = (nj0 + lane < nj1) ? esrc[nj0 + lane] : 0;

        // fold the 8 sub replicas (butterfly over lane bits 3,4,5)
        #pragma unroll
        for (int i = 0; i < 8; ++i) {
            float a = acc[i];
            a += __shfl_xor(a, 8);
            a += __shfl_xor(a, 16);
            a += __shfl_xor(a, 32);
            acc[i] = a;
        }
        if (sub == 0) {        // lanes 0..7 hold the row
            float di = dinv[d];
            float o[8];
            #pragma unroll
            for (int i = 0; i < 8; ++i) o[i] = di * acc[i];
            if (bias != nullptr) {
                #pragma unroll
                for (int i = 0; i < 8; ++i) o[i] += bias[g * 8 + i];
            }
            if (do_relu) {
                #pragma unroll
                for (int i = 0; i < 8; ++i) o[i] = fmaxf(o[i], 0.0f);
            }
            if (houtp != nullptr) {              // fp16 row: 16B per lane
                __half2 ph[4];
                #pragma unroll
                for (int i = 0; i < 4; ++i)
                    ph[i] = __halves2half2(__float2half_rn(o[2 * i]),
                                           __float2half_rn(o[2 * i + 1]));
                *(uint4*)&houtp[(size_t)d * HID + g * 8] = *(uint4*)ph;
            } else {
                float* orow = &outf[(size_t)d * HID + g * 8];
                *(float4*)orow       = make_float4(o[0], o[1], o[2], o[3]);
                *(float4*)(orow + 4) = make_float4(o[4], o[5], o[6], o[7]);
            }
        }
        d = dn; j0 = nj0; j1 = nj1; sp = nsp;
    }
}

extern "C" void kernel_launch(void* const* d_in, const int* in_sizes, int n_in,
                              void* d_out, int out_size, void* d_ws, size_t ws_size,
                              hipStream_t stream) {
    const float* x     = (const float*)d_in[0];   // f32 [N,128]
    const int*   ei    = (const int*)d_in[1];     // int32 [2,E]
    const float* W_in  = (const float*)d_in[2];   // f32 [128,64]
    const float* b_in  = (const float*)d_in[3];   // f32 [64]
    const float* W_h   = (const float*)d_in[4];   // f32 [3,64,64]
    const float* b_h   = (const float*)d_in[5];   // f32 [3,64]
    const float* W_out = (const float*)d_in[6];   // f32 [64,64]

    const int K0 = in_sizes[2] / HID;   // 128
    const int N  = in_sizes[0] / K0;    // 100000
    const int E  = in_sizes[1] / 2;     // 1600000
    const int* srcp = ei;
    const int* dstp = ei + E;

    const int NH = N * HID;
    const size_t Npad = ((size_t)N + 255) & ~(size_t)255;
    const int nbins = (N + BIN_SIZE - 1) >> BIN_SHIFT;   // 196

    float*  ACC = (float*)d_out;                  // final output f32 [N,64]
    __half* h16 = (__half*)d_out;                 // intermediate H fp16 (same storage)

    // ws layout (~20.1MB, inside the proven region):
    float*    dinv   = (float*)d_ws;              // Npad f32          0.4 MB
    __half*   tmp    = (__half*)(dinv + Npad);    // NH half          12.8 MB
    unsigned* packed = (unsigned*)tmp;            // E u32 (ALIASES tmp: CSR build
                                                  //  finishes before first gemm)
    int*      rp     = (int*)(tmp + NH);          // Npad+256          0.4 MB
    int*      esrc   = rp + Npad + 256;           // E                 6.4 MB
    int*      binCount  = esrc + E;               // 1024
    int*      binOff    = binCount + 1024;        // 1025
    int*      binCursor = binOff + 1026;          // 1024
    uintptr_t wf_addr = (uintptr_t)(binCursor + 1024);
    wf_addr = (wf_addr + 15) & ~(uintptr_t)15;
    __half*   wfrag  = (__half*)wf_addr;          // 3072 x 8 fp16    48 KB

    const int tgrid = (N + 127) / 128;
    const int agrid = 2048;                       // persistent waves
    const int sgrid = (E + SC_TILE - 1) / SC_TILE;

    // ---- W fragment prep + counting-sort CSR build (fused) ----
    wfrag_prep<<<48, 64, 0, stream>>>(W_in, W_h, W_out, wfrag);
    zero_i<<<1, 256, 0, stream>>>(binCount, nbins);
    bin_count<<<784, 256, 0, stream>>>(dstp, binCount, E, nbins);
    bin_scan<<<1, 256, 0, stream>>>(binCount, binOff, binCursor, nbins, E);
    bin_scatter<<<sgrid, 256, 0, stream>>>(srcp, dstp, binCursor, packed, E, nbins);
    csr_build<<<nbins, 256, 0, stream>>>(packed, binOff, rp, esrc, dinv, N, E);

    // ---- 5 GCN convs (MFMA GEMMs; fp16 inter-layer H) ----
    gemm_mfma<true, 4><<<tgrid, 256, 0, stream>>>(x, wfrag, dinv, tmp, N);
    agg_csr<<<agrid, 256, 0, stream>>>(tmp, rp, esrc, dinv, b_in, nullptr, h16, N, 0);
    for (int l = 0; l < 3; ++l) {
        gemm_mfma<false, 2><<<tgrid, 256, 0, stream>>>(
            h16, wfrag + (size_t)(1024 + l * 512) * 8, dinv, tmp, N);
        agg_csr<<<agrid, 256, 0, stream>>>(tmp, rp, esrc, dinv, b_h + (size_t)l * HID,
                                           nullptr, h16, N, 1);
    }
    gemm_mfma<false, 2><<<tgrid, 256, 0, stream>>>(
        h16, wfrag + (size_t)2560 * 8, dinv, tmp, N);
    agg_csr<<<agrid, 256, 0, stream>>>(tmp, rp, esrc, dinv, nullptr, ACC, nullptr, N, 0);
}